// Round 9
// baseline (294.931 us; speedup 1.0000x reference)
//
#include <hip/hip_runtime.h>
#include <hip/hip_fp16.h>
#include <cstddef>

// ---------------------------------------------------------------------------
// CrossAttention, f16 MFMA, round 9.
//   B=2, Sq=Sk=2048, D=1024, H=16, Dh=64
// vs r8:
//  - attn: K/V LDS staging + per-iter barriers DELETED. Each wave streams its
//    own 16-k slice straight from global (L2-resident), K prefetched 1 iter
//    ahead in regs. k-loop has zero barriers / zero LDS ops. LDS only for
//    Q-stage + final cross-wave reduction.
//  - cvt3 + wtrans4 fused into one flat-grid prep kernel (one fewer launch).
// Layouts (16x16 MFMA): C/D col=lane&15, row=quad*4+reg.
//   x32 A/B: [idx=lane&15][k=quad*8+j (8)] ; x16 A/B: [idx=lane&15][k=quad*4+j]
// ---------------------------------------------------------------------------

#define B_   2
#define S_   2048
#define D_   1024
#define H_   16
#define DH_  64

typedef _Float16 half8 __attribute__((ext_vector_type(8)));
typedef _Float16 half4 __attribute__((ext_vector_type(4)));
typedef float floatx4 __attribute__((ext_vector_type(4)));

#define MFMA32(a, b, c) __builtin_amdgcn_mfma_f32_16x16x32_f16((a), (b), (c), 0, 0, 0)
#define MFMA16(a, b, c) __builtin_amdgcn_mfma_f32_16x16x16f16((a), (b), (c), 0, 0, 0)

// ---- fused prep: blocks [0,6144) = fp32->f16 cvt of q,k,v ; [6144,7168) =
//      64x64 transpose tiles of the 4 weight matrices ----
__global__ __launch_bounds__(256) void prep(
    const float* __restrict__ q, const float* __restrict__ k,
    const float* __restrict__ v,
    __half* __restrict__ qf, __half* __restrict__ kf, __half* __restrict__ vf,
    const float* __restrict__ Wq, const float* __restrict__ Wk,
    const float* __restrict__ Wv, const float* __restrict__ Wo,
    __half* __restrict__ Wtq, __half* __restrict__ Wtk,
    __half* __restrict__ Wtv, __half* __restrict__ Wto)
{
    __shared__ __align__(16) __half T[64][72];
    const int tid = threadIdx.x;
    const int bz = blockIdx.x;
    if (bz < 6144) {
        const float* srcs[3] = {q, k, v};
        __half* dsts[3] = {qf, kf, vf};
        const int z = bz >> 11;                  // /2048
        const int i = (bz & 2047) * 256 + tid;
        const float4* s = (const float4*)srcs[z];
        const float4 a = s[2 * i], b = s[2 * i + 1];
        half8 h;
        h[0] = (_Float16)a.x; h[1] = (_Float16)a.y; h[2] = (_Float16)a.z; h[3] = (_Float16)a.w;
        h[4] = (_Float16)b.x; h[5] = (_Float16)b.y; h[6] = (_Float16)b.z; h[7] = (_Float16)b.w;
        *(half8*)&dsts[z][(size_t)i * 8] = h;
        return;
    }
    const int idx = bz - 6144;                   // 0..1023
    const float* Ws[4] = {Wq, Wk, Wv, Wo};
    __half* Wts[4] = {Wtq, Wtk, Wtv, Wto};
    const float* W = Ws[idx >> 8];
    __half* Wt = Wts[idx >> 8];
    const int r = idx & 255;
    const int n0 = (r & 15) * 64, k0 = (r >> 4) * 64;
    #pragma unroll
    for (int p = 0; p < 4; ++p) {
        const int c = tid + p * 256;
        const int kr = c >> 4, nc = (c & 15) * 4;
        const float4 a = *(const float4*)&W[(size_t)(k0 + kr) * D_ + n0 + nc];
        T[nc + 0][kr] = __float2half(a.x);
        T[nc + 1][kr] = __float2half(a.y);
        T[nc + 2][kr] = __float2half(a.z);
        T[nc + 3][kr] = __float2half(a.w);
    }
    __syncthreads();
    #pragma unroll
    for (int p = 0; p < 2; ++p) {
        const int c = tid + p * 256;
        const int nr = c >> 3, kc = (c & 7) * 8;
        *(half8*)&Wt[(size_t)(n0 + nr) * D_ + k0 + kc] = *(const half8*)&T[nr][kc];
    }
}

// ---- 128x128 f16 GEMM core, register-prefetch pipelined (r6/r8 proven) ----
__device__ __forceinline__ void gemm_core(
    const __half* __restrict__ A, const __half* __restrict__ Bt,
    const float* __restrict__ bias, void* __restrict__ dst,
    const int mode, const float oscale)
{
    __shared__ __align__(16) char gsm[36864];
    __half (*As)[72] = (__half(*)[72])gsm;
    __half (*Bs)[72] = (__half(*)[72])(gsm + 18432);

    const int tid = threadIdx.x;
    const int m0 = blockIdx.y * 128, n0 = blockIdx.x * 128;
    const int lane = tid & 63, wv = tid >> 6;
    const int quad = lane >> 4, lr = lane & 15;
    const int wm0 = (wv >> 1) * 64, wn0 = (wv & 1) * 64;

    floatx4 acc[4][4];
    #pragma unroll
    for (int i = 0; i < 4; ++i)
        #pragma unroll
        for (int j = 0; j < 4; ++j)
            acc[i][j] = (floatx4){0.f, 0.f, 0.f, 0.f};

    half8 pa[4], pb[4];
    #pragma unroll
    for (int p = 0; p < 4; ++p) {
        const int c = tid + p * 256;
        const int row = c >> 3, seg = (c & 7) * 8;
        pa[p] = *(const half8*)&A [(size_t)(m0 + row) * D_ + seg];
        pb[p] = *(const half8*)&Bt[(size_t)(n0 + row) * D_ + seg];
    }

    for (int k0 = 0; k0 < D_; k0 += 64) {
        __syncthreads();
        #pragma unroll
        for (int p = 0; p < 4; ++p) {
            const int c = tid + p * 256;
            const int row = c >> 3, seg = (c & 7) * 8;
            *(half8*)&As[row][seg] = pa[p];
            *(half8*)&Bs[row][seg] = pb[p];
        }
        if (k0 + 64 < D_) {
            #pragma unroll
            for (int p = 0; p < 4; ++p) {
                const int c = tid + p * 256;
                const int row = c >> 3, seg = (c & 7) * 8;
                pa[p] = *(const half8*)&A [(size_t)(m0 + row) * D_ + k0 + 64 + seg];
                pb[p] = *(const half8*)&Bt[(size_t)(n0 + row) * D_ + k0 + 64 + seg];
            }
        }
        __syncthreads();
        #pragma unroll
        for (int ks = 0; ks < 2; ++ks) {
            const int ko = quad * 8 + ks * 32;
            half8 af[4], bf[4];
            #pragma unroll
            for (int i = 0; i < 4; ++i) af[i] = *(const half8*)&As[wm0 + i * 16 + lr][ko];
            #pragma unroll
            for (int j = 0; j < 4; ++j) bf[j] = *(const half8*)&Bs[wn0 + j * 16 + lr][ko];
            #pragma unroll
            for (int i = 0; i < 4; ++i)
                #pragma unroll
                for (int j = 0; j < 4; ++j)
                    acc[i][j] = MFMA32(af[i], bf[j], acc[i][j]);
        }
    }

    if (mode == 1) {
        float* out = (float*)dst;
        #pragma unroll
        for (int i = 0; i < 4; ++i) {
            #pragma unroll
            for (int j = 0; j < 4; ++j) {
                const int col = n0 + wn0 + j * 16 + lr;
                const float bval = bias[col];
                #pragma unroll
                for (int r = 0; r < 4; ++r) {
                    const int m = m0 + wm0 + i * 16 + quad * 4 + r;
                    out[(size_t)m * D_ + col] = acc[i][j][r] + bval;
                }
            }
        }
        return;
    }

    __syncthreads();
    __half (*Ct)[136] = (__half(*)[136])gsm;
    #pragma unroll
    for (int i = 0; i < 4; ++i) {
        #pragma unroll
        for (int j = 0; j < 4; ++j) {
            const int nl = wn0 + j * 16 + lr;
            const float bval = bias[n0 + nl];
            #pragma unroll
            for (int r = 0; r < 4; ++r) {
                const int ml = wm0 + i * 16 + quad * 4 + r;
                const _Float16 hv = (_Float16)((acc[i][j][r] + bval) * oscale);
                if (mode == 0) Ct[ml][nl] = hv;
                else           Ct[nl][ml] = hv;
            }
        }
    }
    __syncthreads();
    __half* oh = (__half*)dst;
    #pragma unroll
    for (int p = 0; p < 8; ++p) {
        const int row = (tid >> 4) + p * 16;
        const int cs  = (tid & 15) * 8;
        const half8 vls = *(const half8*)&Ct[row][cs];
        if (mode == 0) {
            const int m = m0 + row, col = n0 + cs;
            const int b = m >> 11, s = m & (S_ - 1);
            const int h = col >> 6, d = col & 63;
            *(half8*)&oh[(((size_t)(b * H_ + h) * S_ + s) << 6) + d] = vls;
        } else {
            const int col = n0 + row, m = m0 + cs;
            const int b = m >> 11, s = m & (S_ - 1);
            const int h = col >> 6, d = col & 63;
            *(half8*)&oh[((size_t)(b * H_ + h) * DH_ + d) * S_ + s] = vls;
        }
    }
}

__global__ __launch_bounds__(256) void gemm_proj(
    const __half* __restrict__ qf, const __half* __restrict__ kf,
    const __half* __restrict__ vf,
    const __half* __restrict__ Wtq, const __half* __restrict__ Wtk,
    const __half* __restrict__ Wtv,
    const float* __restrict__ bq, const float* __restrict__ bk,
    const float* __restrict__ bv,
    __half* __restrict__ qhf, __half* __restrict__ khf, __half* __restrict__ vht)
{
    const __half* As[3] = {qf, kf, vf};
    const __half* Bts[3] = {Wtq, Wtk, Wtv};
    const float* bs[3] = {bq, bk, bv};
    __half* ds[3] = {qhf, khf, vht};
    const int z = blockIdx.z;
    gemm_core(As[z], Bts[z], bs[z], ds[z], z == 2 ? 2 : 0,
              z == 0 ? 0.1803368801111244f : 1.0f);   // 0.125*log2(e)
}

__global__ __launch_bounds__(256) void gemm_final(
    const __half* __restrict__ attf, const __half* __restrict__ Wto,
    const float* __restrict__ bo, float* __restrict__ out)
{
    gemm_core(attf, Wto, bo, out, 1, 1.0f);
}

// ---- flash attention, barrier-free k-loop, KV direct from global ----
// qhf/khf: [B,H,S,64] f16 (Q pre-scaled 0.125*log2e). vht: [B,H,64,S].
// Block = 64 q-rows x full 2048 k. Wave w owns k rows {kt + w*16 + lr}.
__global__ __launch_bounds__(256) void attn_f16(
    const __half* __restrict__ qhf, const __half* __restrict__ khf,
    const __half* __restrict__ vht, __half* __restrict__ attf)
{
    __shared__ __align__(16) char smem[31232];
    __half (*Qs)[72] = (__half(*)[72])smem;              // [64 q][64 d] (stage only)

    const int tid = threadIdx.x;
    const int lane = tid & 63, wv = tid >> 6;
    const int quad = lane >> 4, lr = lane & 15;
    const int bh = blockIdx.y;
    const int q0 = blockIdx.x * 64;
    const size_t hbase = (size_t)bh * S_ * DH_;

    // ---- stage Q once; Q B-frags (x32 layout) into registers ----
    #pragma unroll
    for (int p = 0; p < 2; ++p) {
        const int c = tid + p * 256;
        const int row = c >> 3, seg = (c & 7) * 8;
        *(half8*)&Qs[row][seg] = *(const half8*)&qhf[hbase + (size_t)(q0 + row) * DH_ + seg];
    }
    __syncthreads();
    half8 qB[4][2];
    #pragma unroll
    for (int qs = 0; qs < 4; ++qs)
        #pragma unroll
        for (int ks = 0; ks < 2; ++ks)
            qB[qs][ks] = *(const half8*)&Qs[qs * 16 + lr][quad * 8 + ks * 32];
    __syncthreads();   // Qs free for reduction overlay later

    float lp[4] = {0.f, 0.f, 0.f, 0.f};
    floatx4 O[4][4];
    #pragma unroll
    for (int i = 0; i < 4; ++i)
        #pragma unroll
        for (int j = 0; j < 4; ++j)
            O[i][j] = (floatx4){0.f, 0.f, 0.f, 0.f};

    // wave-private global pointers
    const __half* kp = khf + hbase + (size_t)(wv * 16 + lr) * DH_ + quad * 8;
    const __half* vp = vht + hbase + (size_t)lr * S_ + wv * 16 + quad * 4;

    // prefetch K fragment for kt=0
    half8 cK0 = *(const half8*)(kp);
    half8 cK1 = *(const half8*)(kp + 32);

    for (int kt = 0; kt < S_; kt += 64) {
        // current V fragments (consumed after exp — natural latency cover)
        half4 cV[4];
        #pragma unroll
        for (int ds = 0; ds < 4; ++ds)
            cV[ds] = *(const half4*)(vp + (size_t)ds * 16 * S_ + kt);

        // next-iter K prefetch
        half8 nK0, nK1;
        if (kt + 64 < S_) {
            const __half* kn = kp + (size_t)(kt + 64) * DH_;
            nK0 = *(const half8*)(kn);
            nK1 = *(const half8*)(kn + 32);
        }

        // ---- S^T = K Q^T : this wave's 16 k-rows x 64 q ----
        floatx4 s4[4];
        #pragma unroll
        for (int qs = 0; qs < 4; ++qs) s4[qs] = (floatx4){0.f, 0.f, 0.f, 0.f};
        #pragma unroll
        for (int qs = 0; qs < 4; ++qs) s4[qs] = MFMA32(cK0, qB[qs][0], s4[qs]);
        #pragma unroll
        for (int qs = 0; qs < 4; ++qs) s4[qs] = MFMA32(cK1, qB[qs][1], s4[qs]);

        // ---- P^T = exp2(S^T); partial col sums; pack x16 B-frags ----
        half4 pB[4];
        #pragma unroll
        for (int qs = 0; qs < 4; ++qs) {
            #pragma unroll
            for (int r = 0; r < 4; ++r) {
                const float p = __builtin_amdgcn_exp2f(s4[qs][r]);
                lp[qs] += p;
                pB[qs][r] = (_Float16)p;
            }
        }

        // ---- O^T += V^T P^T over wave's 16-k slice (x16) ----
        #pragma unroll
        for (int ds = 0; ds < 4; ++ds) {
            #pragma unroll
            for (int qs = 0; qs < 4; ++qs)
                O[ds][qs] = MFMA16(cV[ds], pB[qs], O[ds][qs]);
        }

        cK0 = nK0; cK1 = nK1;
    }

    // ---- cross-wave reduction (overlay buffers on smem) ----
    float* L    = (float*)(smem + 17408);      // [16][64]
    float* invL = (float*)(smem + 21504);      // [64]
    float (*R)[68] = (float(*)[68])smem;       // [64][68]
    __half (*F)[72] = (__half(*)[72])(smem + 22016);  // [64 q][64 d]

    #pragma unroll
    for (int qs = 0; qs < 4; ++qs)
        L[(wv * 4 + quad) * 64 + qs * 16 + lr] = lp[qs];
    __syncthreads();
    if (tid < 64) {
        float s = 0.f;
        #pragma unroll
        for (int i = 0; i < 16; ++i) s += L[i * 64 + tid];
        invL[tid] = 1.0f / s;
    }
    __syncthreads();

    const int qc = tid & 63, dg = tid >> 6;
    const float il = invL[qc];

    #pragma unroll
    for (int ds = 0; ds < 4; ++ds) {
        __syncthreads();
        #pragma unroll
        for (int qs = 0; qs < 4; ++qs)
            #pragma unroll
            for (int r = 0; r < 4; ++r)
                R[wv * 16 + quad * 4 + r][qs * 16 + lr] = O[ds][qs][r];
        __syncthreads();
        half4 hv;
        #pragma unroll
        for (int rr = 0; rr < 4; ++rr) {
            const int row = dg * 4 + rr;
            const float v = R[row][qc] + R[16 + row][qc] + R[32 + row][qc] + R[48 + row][qc];
            hv[rr] = (_Float16)(v * il);
        }
        *(half4*)&F[qc][ds * 16 + dg * 4] = hv;
    }
    __syncthreads();

    const int b = bh >> 4, h = bh & 15;
    const int qrow = tid >> 2, dseg = (tid & 3) * 16;
    __half* dstp = &attf[(((size_t)(b * S_ + q0 + qrow)) << 10) + h * DH_ + dseg];
    *(half8*)&dstp[0] = *(const half8*)&F[qrow][dseg];
    *(half8*)&dstp[8] = *(const half8*)&F[qrow][dseg + 8];
}

extern "C" void kernel_launch(void* const* d_in, const int* in_sizes, int n_in,
                              void* d_out, int out_size, void* d_ws, size_t ws_size,
                              hipStream_t stream) {
    const float* q  = (const float*)d_in[0];
    const float* k  = (const float*)d_in[1];
    const float* v  = (const float*)d_in[2];
    const float* Wq = (const float*)d_in[3];
    const float* bq = (const float*)d_in[4];
    const float* Wk = (const float*)d_in[5];
    const float* bk = (const float*)d_in[6];
    const float* Wv = (const float*)d_in[7];
    const float* bv = (const float*)d_in[8];
    const float* Wo = (const float*)d_in[9];
    const float* bo = (const float*)d_in[10];
    float* out = (float*)d_out;

    __half* ws = (__half*)d_ws;
    const size_t NE = (size_t)B_ * S_ * D_;     // 4,194,304
    __half* qf   = ws;
    __half* kf   = ws + NE;
    __half* vf   = ws + 2 * NE;
    __half* qhf  = ws + 3 * NE;
    __half* khf  = ws + 4 * NE;
    __half* vht  = ws + 5 * NE;
    __half* attf = ws + 6 * NE;
    __half* Wtq  = ws + 7 * NE;
    __half* Wtk  = Wtq + (size_t)D_ * D_;
    __half* Wtv  = Wtk + (size_t)D_ * D_;
    __half* Wto  = Wtv + (size_t)D_ * D_;

    const dim3 blk(256);
    prep<<<dim3(7168), blk, 0, stream>>>(q, k, v, qf, kf, vf,
                                         Wq, Wk, Wv, Wo, Wtq, Wtk, Wtv, Wto);

    gemm_proj<<<dim3(D_ / 128, (B_ * S_) / 128, 3), blk, 0, stream>>>(
        qf, kf, vf, Wtq, Wtk, Wtv, bq, bk, bv, qhf, khf, vht);

    attn_f16<<<dim3(S_ / 64, B_ * H_), blk, 0, stream>>>(qhf, khf, vht, attf);

    gemm_final<<<dim3(D_ / 128, (B_ * S_) / 128), blk, 0, stream>>>(attf, Wto, bo, out);
}

// Round 10
// 234.135 us; speedup vs baseline: 1.2597x; 1.2597x over previous
//
#include <hip/hip_runtime.h>
#include <hip/hip_fp16.h>
#include <cstddef>

// ---------------------------------------------------------------------------
// CrossAttention, f16 MFMA, round 10 (= r8 + attn BK=128 + gemm swizzle).
//   B=2, Sq=Sk=2048, D=1024, H=16, Dh=64
// r9 lesson: never drop cooperative LDS staging for scattered per-wave global
// streams (attn 66->121 us). This round keeps r8's staging pipeline but:
//  - attn: k-tile 128 (wave owns 32 k-rows, 2 groups of 16) -> half the
//    barrier events per unit work.
//  - gemm: block-id swizzle (4m x 8n groups) for per-XCD L2 locality.
// Layouts (16x16 MFMA): C/D col=lane&15, row=quad*4+reg.
//   x32 A/B: [idx=lane&15][k=quad*8+j (8)] ; x16 A/B: [idx=lane&15][k=quad*4+j]
// ---------------------------------------------------------------------------

#define B_   2
#define S_   2048
#define D_   1024
#define H_   16
#define DH_  64

typedef _Float16 half8 __attribute__((ext_vector_type(8)));
typedef _Float16 half4 __attribute__((ext_vector_type(4)));
typedef float floatx4 __attribute__((ext_vector_type(4)));

#define MFMA32(a, b, c) __builtin_amdgcn_mfma_f32_16x16x32_f16((a), (b), (c), 0, 0, 0)
#define MFMA16(a, b, c) __builtin_amdgcn_mfma_f32_16x16x16f16((a), (b), (c), 0, 0, 0)

// ---- fp32 -> f16, 3 tensors in one dispatch (y selects) ----
__global__ __launch_bounds__(256) void cvt3(
    const float* __restrict__ q, const float* __restrict__ k,
    const float* __restrict__ v,
    __half* __restrict__ qf, __half* __restrict__ kf, __half* __restrict__ vf)
{
    const float* srcs[3] = {q, k, v};
    __half* dsts[3] = {qf, kf, vf};
    const int z = blockIdx.y;
    const int i = blockIdx.x * 256 + threadIdx.x;
    const float4* s = (const float4*)srcs[z];
    const float4 a = s[2 * i], b = s[2 * i + 1];
    half8 h;
    h[0] = (_Float16)a.x; h[1] = (_Float16)a.y; h[2] = (_Float16)a.z; h[3] = (_Float16)a.w;
    h[4] = (_Float16)b.x; h[5] = (_Float16)b.y; h[6] = (_Float16)b.z; h[7] = (_Float16)b.w;
    *(half8*)&dsts[z][(size_t)i * 8] = h;
}

// ---- W [K][N] fp32 -> Wt [N][K] f16, 64x64 tiles, 4 weights via z ----
__global__ __launch_bounds__(256) void wtrans4(
    const float* __restrict__ Wq, const float* __restrict__ Wk,
    const float* __restrict__ Wv, const float* __restrict__ Wo,
    __half* __restrict__ Wtq, __half* __restrict__ Wtk,
    __half* __restrict__ Wtv, __half* __restrict__ Wto)
{
    __shared__ __align__(16) __half T[64][72];
    const float* Ws[4] = {Wq, Wk, Wv, Wo};
    __half* Wts[4] = {Wtq, Wtk, Wtv, Wto};
    const float* W = Ws[blockIdx.z];
    __half* Wt = Wts[blockIdx.z];
    const int tid = threadIdx.x;
    const int n0 = blockIdx.x * 64, k0 = blockIdx.y * 64;
    #pragma unroll
    for (int p = 0; p < 4; ++p) {
        const int c = tid + p * 256;
        const int kr = c >> 4, nc = (c & 15) * 4;
        const float4 a = *(const float4*)&W[(size_t)(k0 + kr) * D_ + n0 + nc];
        T[nc + 0][kr] = __float2half(a.x);
        T[nc + 1][kr] = __float2half(a.y);
        T[nc + 2][kr] = __float2half(a.z);
        T[nc + 3][kr] = __float2half(a.w);
    }
    __syncthreads();
    #pragma unroll
    for (int p = 0; p < 2; ++p) {
        const int c = tid + p * 256;
        const int nr = c >> 3, kc = (c & 7) * 8;
        *(half8*)&Wt[(size_t)(n0 + nr) * D_ + k0 + kc] = *(const half8*)&T[nr][kc];
    }
}

// ---- 128x128 f16 GEMM core, register-prefetch pipelined (r6/r8 proven) ----
// m0/n0 passed in (swizzled by wrapper).
__device__ __forceinline__ void gemm_core(
    const __half* __restrict__ A, const __half* __restrict__ Bt,
    const float* __restrict__ bias, void* __restrict__ dst,
    const int mode, const float oscale, const int m0, const int n0)
{
    __shared__ __align__(16) char gsm[36864];
    __half (*As)[72] = (__half(*)[72])gsm;
    __half (*Bs)[72] = (__half(*)[72])(gsm + 18432);

    const int tid = threadIdx.x;
    const int lane = tid & 63, wv = tid >> 6;
    const int quad = lane >> 4, lr = lane & 15;
    const int wm0 = (wv >> 1) * 64, wn0 = (wv & 1) * 64;

    floatx4 acc[4][4];
    #pragma unroll
    for (int i = 0; i < 4; ++i)
        #pragma unroll
        for (int j = 0; j < 4; ++j)
            acc[i][j] = (floatx4){0.f, 0.f, 0.f, 0.f};

    half8 pa[4], pb[4];
    #pragma unroll
    for (int p = 0; p < 4; ++p) {
        const int c = tid + p * 256;
        const int row = c >> 3, seg = (c & 7) * 8;
        pa[p] = *(const half8*)&A [(size_t)(m0 + row) * D_ + seg];
        pb[p] = *(const half8*)&Bt[(size_t)(n0 + row) * D_ + seg];
    }

    for (int k0 = 0; k0 < D_; k0 += 64) {
        __syncthreads();
        #pragma unroll
        for (int p = 0; p < 4; ++p) {
            const int c = tid + p * 256;
            const int row = c >> 3, seg = (c & 7) * 8;
            *(half8*)&As[row][seg] = pa[p];
            *(half8*)&Bs[row][seg] = pb[p];
        }
        if (k0 + 64 < D_) {
            #pragma unroll
            for (int p = 0; p < 4; ++p) {
                const int c = tid + p * 256;
                const int row = c >> 3, seg = (c & 7) * 8;
                pa[p] = *(const half8*)&A [(size_t)(m0 + row) * D_ + k0 + 64 + seg];
                pb[p] = *(const half8*)&Bt[(size_t)(n0 + row) * D_ + k0 + 64 + seg];
            }
        }
        __syncthreads();
        #pragma unroll
        for (int ks = 0; ks < 2; ++ks) {
            const int ko = quad * 8 + ks * 32;
            half8 af[4], bf[4];
            #pragma unroll
            for (int i = 0; i < 4; ++i) af[i] = *(const half8*)&As[wm0 + i * 16 + lr][ko];
            #pragma unroll
            for (int j = 0; j < 4; ++j) bf[j] = *(const half8*)&Bs[wn0 + j * 16 + lr][ko];
            #pragma unroll
            for (int i = 0; i < 4; ++i)
                #pragma unroll
                for (int j = 0; j < 4; ++j)
                    acc[i][j] = MFMA32(af[i], bf[j], acc[i][j]);
        }
    }

    if (mode == 1) {
        float* out = (float*)dst;
        #pragma unroll
        for (int i = 0; i < 4; ++i) {
            #pragma unroll
            for (int j = 0; j < 4; ++j) {
                const int col = n0 + wn0 + j * 16 + lr;
                const float bval = bias[col];
                #pragma unroll
                for (int r = 0; r < 4; ++r) {
                    const int m = m0 + wm0 + i * 16 + quad * 4 + r;
                    out[(size_t)m * D_ + col] = acc[i][j][r] + bval;
                }
            }
        }
        return;
    }

    __syncthreads();
    __half (*Ct)[136] = (__half(*)[136])gsm;
    #pragma unroll
    for (int i = 0; i < 4; ++i) {
        #pragma unroll
        for (int j = 0; j < 4; ++j) {
            const int nl = wn0 + j * 16 + lr;
            const float bval = bias[n0 + nl];
            #pragma unroll
            for (int r = 0; r < 4; ++r) {
                const int ml = wm0 + i * 16 + quad * 4 + r;
                const _Float16 hv = (_Float16)((acc[i][j][r] + bval) * oscale);
                if (mode == 0) Ct[ml][nl] = hv;
                else           Ct[nl][ml] = hv;
            }
        }
    }
    __syncthreads();
    __half* oh = (__half*)dst;
    #pragma unroll
    for (int p = 0; p < 8; ++p) {
        const int row = (tid >> 4) + p * 16;
        const int cs  = (tid & 15) * 8;
        const half8 vls = *(const half8*)&Ct[row][cs];
        if (mode == 0) {
            const int m = m0 + row, col = n0 + cs;
            const int b = m >> 11, s = m & (S_ - 1);
            const int h = col >> 6, d = col & 63;
            *(half8*)&oh[(((size_t)(b * H_ + h) * S_ + s) << 6) + d] = vls;
        } else {
            const int col = n0 + row, m = m0 + cs;
            const int b = m >> 11, s = m & (S_ - 1);
            const int h = col >> 6, d = col & 63;
            *(half8*)&oh[((size_t)(b * H_ + h) * DH_ + d) * S_ + s] = vls;
        }
    }
}

// swizzled (m0,n0): 32 consecutive block-ids cover 4 m-tiles x 8 n-tiles
__device__ __forceinline__ void swizzle_mn(int& m0, int& n0) {
    const int id = blockIdx.y * gridDim.x + blockIdx.x;   // 0..255
    const int grp = id >> 5, within = id & 31;
    m0 = (grp * 4 + (within & 3)) * 128;
    n0 = (within >> 2) * 128;
}

__global__ __launch_bounds__(256) void gemm_proj(
    const __half* __restrict__ qf, const __half* __restrict__ kf,
    const __half* __restrict__ vf,
    const __half* __restrict__ Wtq, const __half* __restrict__ Wtk,
    const __half* __restrict__ Wtv,
    const float* __restrict__ bq, const float* __restrict__ bk,
    const float* __restrict__ bv,
    __half* __restrict__ qhf, __half* __restrict__ khf, __half* __restrict__ vht)
{
    const __half* As[3] = {qf, kf, vf};
    const __half* Bts[3] = {Wtq, Wtk, Wtv};
    const float* bs[3] = {bq, bk, bv};
    __half* ds[3] = {qhf, khf, vht};
    const int z = blockIdx.z;
    int m0, n0; swizzle_mn(m0, n0);
    gemm_core(As[z], Bts[z], bs[z], ds[z], z == 2 ? 2 : 0,
              z == 0 ? 0.1803368801111244f : 1.0f, m0, n0);  // 0.125*log2(e)
}

__global__ __launch_bounds__(256) void gemm_final(
    const __half* __restrict__ attf, const __half* __restrict__ Wto,
    const float* __restrict__ bo, float* __restrict__ out)
{
    int m0, n0; swizzle_mn(m0, n0);
    gemm_core(attf, Wto, bo, out, 1, 1.0f, m0, n0);
}

// ---- flash attention, BK=128, register-resident P, prefetch staging ----
// qhf/khf: [B,H,S,64] f16 (Q pre-scaled 0.125*log2e). vht: [B,H,64,S].
// Block = 64 q x 2048 k in tiles of 128; wave w owns k-rows w*32..w*32+31
// (two 16-row groups) of each tile.
__global__ __launch_bounds__(256) void attn_f16(
    const __half* __restrict__ qhf, const __half* __restrict__ khf,
    const __half* __restrict__ vht, __half* __restrict__ attf)
{
    __shared__ __align__(16) char smem[35840];
    __half (*Ks)[72]  = (__half(*)[72])smem;             // [128 k][64 d]
    __half (*Vs)[136] = (__half(*)[136])(smem + 18432);  // [64 d][128 s]
    __half (*Qs)[72]  = (__half(*)[72])smem;             // stage overlay

    const int tid = threadIdx.x;
    const int lane = tid & 63, wv = tid >> 6;
    const int quad = lane >> 4, lr = lane & 15;
    const int bh = blockIdx.y;
    const int q0 = blockIdx.x * 64;
    const size_t hbase = (size_t)bh * S_ * DH_;

    // ---- stage Q once (into Ks region); Q B-frags into registers ----
    #pragma unroll
    for (int p = 0; p < 2; ++p) {
        const int c = tid + p * 256;
        const int row = c >> 3, seg = (c & 7) * 8;
        *(half8*)&Qs[row][seg] = *(const half8*)&qhf[hbase + (size_t)(q0 + row) * DH_ + seg];
    }
    __syncthreads();
    half8 qB[4][2];
    #pragma unroll
    for (int qs = 0; qs < 4; ++qs)
        #pragma unroll
        for (int ks = 0; ks < 2; ++ks)
            qB[qs][ks] = *(const half8*)&Qs[qs * 16 + lr][quad * 8 + ks * 32];
    __syncthreads();   // Qs region free for Ks

    float lp[4] = {0.f, 0.f, 0.f, 0.f};
    floatx4 O[4][4];
    #pragma unroll
    for (int i = 0; i < 4; ++i)
        #pragma unroll
        for (int j = 0; j < 4; ++j)
            O[i][j] = (floatx4){0.f, 0.f, 0.f, 0.f};

    // prefetch kt = 0 tile: K 128x64, V 64x128
    half8 pk[4], pv[4];
    #pragma unroll
    for (int p = 0; p < 4; ++p) {
        const int c = tid + p * 256;
        const int krow = c >> 3, kseg = (c & 7) * 8;       // K: 128 rows
        const int vrow = c >> 4, vseg = (c & 15) * 8;      // V: 64 rows x 128
        pk[p] = *(const half8*)&khf[hbase + (size_t)krow * DH_ + kseg];
        pv[p] = *(const half8*)&vht[hbase + (size_t)vrow * S_ + vseg];
    }

    for (int kt = 0; kt < S_; kt += 128) {
        __syncthreads();
        #pragma unroll
        for (int p = 0; p < 4; ++p) {
            const int c = tid + p * 256;
            const int krow = c >> 3, kseg = (c & 7) * 8;
            const int vrow = c >> 4, vseg = (c & 15) * 8;
            *(half8*)&Ks[krow][kseg] = pk[p];
            *(half8*)&Vs[vrow][vseg] = pv[p];
        }
        if (kt + 128 < S_) {
            #pragma unroll
            for (int p = 0; p < 4; ++p) {
                const int c = tid + p * 256;
                const int krow = c >> 3, kseg = (c & 7) * 8;
                const int vrow = c >> 4, vseg = (c & 15) * 8;
                pk[p] = *(const half8*)&khf[hbase + (size_t)(kt + 128 + krow) * DH_ + kseg];
                pv[p] = *(const half8*)&vht[hbase + (size_t)vrow * S_ + kt + 128 + vseg];
            }
        }
        __syncthreads();

        #pragma unroll
        for (int g = 0; g < 2; ++g) {
            const int kr = wv * 32 + g * 16 + lr;
            const half8 aK0 = *(const half8*)&Ks[kr][quad * 8];
            const half8 aK1 = *(const half8*)&Ks[kr][quad * 8 + 32];

            floatx4 s4[4];
            #pragma unroll
            for (int qs = 0; qs < 4; ++qs) s4[qs] = (floatx4){0.f, 0.f, 0.f, 0.f};
            #pragma unroll
            for (int qs = 0; qs < 4; ++qs) s4[qs] = MFMA32(aK0, qB[qs][0], s4[qs]);
            #pragma unroll
            for (int qs = 0; qs < 4; ++qs) s4[qs] = MFMA32(aK1, qB[qs][1], s4[qs]);

            half4 pB[4];
            #pragma unroll
            for (int qs = 0; qs < 4; ++qs) {
                #pragma unroll
                for (int r = 0; r < 4; ++r) {
                    const float p = __builtin_amdgcn_exp2f(s4[qs][r]);
                    lp[qs] += p;
                    pB[qs][r] = (_Float16)p;
                }
            }

            #pragma unroll
            for (int ds = 0; ds < 4; ++ds) {
                const half4 aV = *(const half4*)&Vs[ds * 16 + lr][wv * 32 + g * 16 + quad * 4];
                #pragma unroll
                for (int qs = 0; qs < 4; ++qs)
                    O[ds][qs] = MFMA16(aV, pB[qs], O[ds][qs]);
            }
        }
    }

    // ---- cross-wave reduction (overlay buffers on smem) ----
    __syncthreads();
    float* L    = (float*)(smem + 17408);      // [16][64]
    float* invL = (float*)(smem + 21504);      // [64]
    float (*R)[68] = (float(*)[68])smem;       // [64][68]
    __half (*F)[72] = (__half(*)[72])(smem + 22016);  // [64 q][64 d]

    #pragma unroll
    for (int qs = 0; qs < 4; ++qs)
        L[(wv * 4 + quad) * 64 + qs * 16 + lr] = lp[qs];
    __syncthreads();
    if (tid < 64) {
        float s = 0.f;
        #pragma unroll
        for (int i = 0; i < 16; ++i) s += L[i * 64 + tid];
        invL[tid] = 1.0f / s;
    }
    __syncthreads();

    const int qc = tid & 63, dg = tid >> 6;
    const float il = invL[qc];

    #pragma unroll
    for (int ds = 0; ds < 4; ++ds) {
        __syncthreads();
        #pragma unroll
        for (int qs = 0; qs < 4; ++qs)
            #pragma unroll
            for (int r = 0; r < 4; ++r)
                R[wv * 16 + quad * 4 + r][qs * 16 + lr] = O[ds][qs][r];
        __syncthreads();
        half4 hv;
        #pragma unroll
        for (int rr = 0; rr < 4; ++rr) {
            const int row = dg * 4 + rr;
            const float v = R[row][qc] + R[16 + row][qc] + R[32 + row][qc] + R[48 + row][qc];
            hv[rr] = (_Float16)(v * il);
        }
        *(half4*)&F[qc][ds * 16 + dg * 4] = hv;
    }
    __syncthreads();

    const int b = bh >> 4, h = bh & 15;
    const int qrow = tid >> 2, dseg = (tid & 3) * 16;
    __half* dstp = &attf[(((size_t)(b * S_ + q0 + qrow)) << 10) + h * DH_ + dseg];
    *(half8*)&dstp[0] = *(const half8*)&F[qrow][dseg];
    *(half8*)&dstp[8] = *(const half8*)&F[qrow][dseg + 8];
}

extern "C" void kernel_launch(void* const* d_in, const int* in_sizes, int n_in,
                              void* d_out, int out_size, void* d_ws, size_t ws_size,
                              hipStream_t stream) {
    const float* q  = (const float*)d_in[0];
    const float* k  = (const float*)d_in[1];
    const float* v  = (const float*)d_in[2];
    const float* Wq = (const float*)d_in[3];
    const float* bq = (const float*)d_in[4];
    const float* Wk = (const float*)d_in[5];
    const float* bk = (const float*)d_in[6];
    const float* Wv = (const float*)d_in[7];
    const float* bv = (const float*)d_in[8];
    const float* Wo = (const float*)d_in[9];
    const float* bo = (const float*)d_in[10];
    float* out = (float*)d_out;

    __half* ws = (__half*)d_ws;
    const size_t NE = (size_t)B_ * S_ * D_;     // 4,194,304
    __half* qf   = ws;
    __half* kf   = ws + NE;
    __half* vf   = ws + 2 * NE;
    __half* qhf  = ws + 3 * NE;
    __half* khf  = ws + 4 * NE;
    __half* vht  = ws + 5 * NE;
    __half* attf = ws + 6 * NE;
    __half* Wtq  = ws + 7 * NE;
    __half* Wtk  = Wtq + (size_t)D_ * D_;
    __half* Wtv  = Wtk + (size_t)D_ * D_;
    __half* Wto  = Wtv + (size_t)D_ * D_;

    const dim3 blk(256);
    cvt3<<<dim3((unsigned)(NE / 8 / 256), 3), blk, 0, stream>>>(q, k, v, qf, kf, vf);
    wtrans4<<<dim3(16, 16, 4), blk, 0, stream>>>(Wq, Wk, Wv, Wo, Wtq, Wtk, Wtv, Wto);

    gemm_proj<<<dim3(D_ / 128, (B_ * S_) / 128, 3), blk, 0, stream>>>(
        qf, kf, vf, Wtq, Wtk, Wtv, bq, bk, bv, qhf, khf, vht);

    attn_f16<<<dim3(S_ / 64, B_ * H_), blk, 0, stream>>>(qhf, khf, vht, attf);

    gemm_final<<<dim3(D_ / 128, (B_ * S_) / 128), blk, 0, stream>>>(attf, Wto, bo, out);
}